// Round 2
// baseline (794.023 us; speedup 1.0000x reference)
//
#include <hip/hip_runtime.h>
#include <hip/hip_bf16.h>
#include <cstdint>
#include <cstddef>

// MultiHeadAttention: fp32 in/out (per reference dtypes). B=4, L=2048, D=1024,
// H=16, dk=64. Internally bf16 MFMA with fp32 accumulation.
// Pipeline: wtrans_cvt(W->bf16 W^T) ; per proj: cvt(act->bf16) -> gemm ;
// flash-attn (bf16) ; final gemm -> fp32 out.

typedef unsigned short u16;
typedef __bf16 bf8v __attribute__((ext_vector_type(8)));   // MFMA A/B frag (4 VGPRs)
typedef float f32x4 __attribute__((ext_vector_type(4)));   // MFMA C/D frag

#define D_MODEL 1024
#define NHEAD   16
#define DK      64
#define BATCH   4
#define SEQ     2048
#define ROWS    (BATCH * SEQ)   // 8192

__device__ __forceinline__ u16 f2b(float f) {  // RTNE float->bf16
  union { float f; unsigned int i; } x; x.f = f;
  unsigned int r = x.i + 0x7fffu + ((x.i >> 16) & 1u);
  return (u16)(r >> 16);
}
__device__ __forceinline__ void async16(const void* g, void* l) {
  // width=16 global->LDS DMA; LDS dest = wave-uniform base + lane*16
  __builtin_amdgcn_global_load_lds((const __attribute__((address_space(1))) void*)g,
                                   (__attribute__((address_space(3))) void*)l, 16, 0, 0);
}

// -------- weight transpose + downcast: dst[n][k] = bf16(src[k][n]), 4 mats ------
__global__ void wtrans_cvt_kernel(const float* __restrict__ w0, const float* __restrict__ w1,
                                  const float* __restrict__ w2, const float* __restrict__ w3,
                                  u16* __restrict__ dst4) {
  __shared__ float t[32][33];
  const float* src = (blockIdx.z == 0) ? w0 : (blockIdx.z == 1) ? w1
                   : (blockIdx.z == 2) ? w2 : w3;
  u16* dst = dst4 + (size_t)blockIdx.z * D_MODEL * D_MODEL;
  const int c0 = blockIdx.x * 32, r0 = blockIdx.y * 32;
  for (int i = threadIdx.y; i < 32; i += 8)
    t[i][threadIdx.x] = src[(size_t)(r0 + i) * D_MODEL + c0 + threadIdx.x];
  __syncthreads();
  for (int i = threadIdx.y; i < 32; i += 8)
    dst[(size_t)(c0 + i) * D_MODEL + r0 + threadIdx.x] = f2b(t[threadIdx.x][i]);
}

// -------- activation downcast: bf16 dst[i] = src[i], vectorized x4 --------------
__global__ __launch_bounds__(256) void cvt_f2b_kernel(const float* __restrict__ src,
                                                      u16* __restrict__ dst, int n4) {
  const int i = blockIdx.x * 256 + threadIdx.x;
  if (i < n4) {
    const float4 v = ((const float4*)src)[i];
    ushort4 o;
    o.x = f2b(v.x); o.y = f2b(v.y); o.z = f2b(v.z); o.w = f2b(v.w);
    ((ushort4*)dst)[i] = o;
  }
}

// ---------------- GEMM: out = A[M,1024] @ Bt^T + bias, m97 structure ------------
// A row-major bf16 [M,K=1024]; Bt = B^T row-major bf16 [N=1024,K=1024]; bias fp32.
// mode 0: out bf16 [bh][l][dk]   (Q/K heads-split)
// mode 1: out bf16 [bh][dk][l]   (V transposed per head)
// mode 2: out fp32 [row][1024]   (final projection)
#define BM 128
#define BN 128
#define BK 32

__global__ __launch_bounds__(256) void gemm_bt(const u16* __restrict__ A,
                                               const u16* __restrict__ Bt,
                                               const float* __restrict__ bias,
                                               void* __restrict__ out, int mode) {
  __shared__ __align__(16) u16 As[BM * BK];  // 8 KB, [128 m][32 k]
  __shared__ __align__(16) u16 Bs[BN * BK];  // 8 KB, [128 n][32 k]
  const int tid = threadIdx.x;
  const int lane = tid & 63, wave = tid >> 6;
  const int wm = wave >> 1, wn = wave & 1;          // 2x2 wave grid, 64x64 each
  const int quad = lane >> 4, l16 = lane & 15;
  const int m0 = blockIdx.x * BM, n0 = blockIdx.y * BN;
  const int K = 1024;

  f32x4 acc[4][4];
#pragma unroll
  for (int i = 0; i < 4; i++)
#pragma unroll
    for (int j = 0; j < 4; j++) acc[i][j] = (f32x4){0.f, 0.f, 0.f, 0.f};

  const int srow = tid >> 2;          // 0..63
  const int skof = (tid & 3) * 8;     // k offset (bf16 elems), 16B granularity
  const u16* Ag = A + (size_t)(m0 + srow) * K + skof;
  const u16* Bg = Bt + (size_t)(n0 + srow) * K + skof;

  for (int k0 = 0; k0 < K; k0 += BK) {
    async16(Ag + k0, &As[tid * 8]);
    async16(Ag + (size_t)64 * K + k0, &As[2048 + tid * 8]);
    async16(Bg + k0, &Bs[tid * 8]);
    async16(Bg + (size_t)64 * K + k0, &Bs[2048 + tid * 8]);
    __syncthreads();   // drains vmcnt before s_barrier

    bf8v af[4], bfr[4];
#pragma unroll
    for (int i = 0; i < 4; i++)
      af[i] = *(const bf8v*)&As[(wm * 64 + i * 16 + l16) * BK + quad * 8];
#pragma unroll
    for (int j = 0; j < 4; j++)
      bfr[j] = *(const bf8v*)&Bs[(wn * 64 + j * 16 + l16) * BK + quad * 8];
#pragma unroll
    for (int i = 0; i < 4; i++)
#pragma unroll
      for (int j = 0; j < 4; j++)
        acc[i][j] = __builtin_amdgcn_mfma_f32_16x16x32_bf16(af[i], bfr[j], acc[i][j], 0, 0, 0);
    __syncthreads();
  }

  // epilogue: C layout col=lane&15, row=quad*4+reg  [m89-verified]
#pragma unroll
  for (int j = 0; j < 4; j++) {
    const int n = n0 + wn * 64 + j * 16 + l16;
    const float bv = bias[n];
#pragma unroll
    for (int i = 0; i < 4; i++) {
      const int gr0 = m0 + wm * 64 + i * 16 + quad * 4;
#pragma unroll
      for (int r = 0; r < 4; r++) {
        const int row = gr0 + r;
        const float val = acc[i][j][r] + bv;
        if (mode == 2) {
          ((float*)out)[(size_t)row * D_MODEL + n] = val;
        } else {
          const int b = row >> 11, l = row & 2047;
          const int h = n >> 6, d = n & 63;
          if (mode == 0)
            ((u16*)out)[(((size_t)(b * NHEAD + h) * SEQ + l) << 6) + d] = f2b(val);
          else
            ((u16*)out)[(((size_t)(b * NHEAD + h) * DK + d) << 11) + l] = f2b(val);
        }
      }
    }
  }
}

// ---------------- flash attention: one block per (64 q rows, bh) ----------------
// Q,K: [bh][SEQ][DK] bf16.  Vt: [bh][DK][SEQ] bf16.  ctx: [B*SEQ][D_MODEL] bf16.
__global__ __launch_bounds__(256) void attn_kernel(const u16* __restrict__ Q,
                                                   const u16* __restrict__ K,
                                                   const u16* __restrict__ Vt,
                                                   u16* __restrict__ ctx) {
  const int bh = blockIdx.y;
  const int qb = blockIdx.x * 64;
  const int tid = threadIdx.x;
  const int lane = tid & 63, wave = tid >> 6;   // 4 waves, 16 q rows each
  const int quad = lane >> 4, l16 = lane & 15;
  const u16* Qh = Q + (size_t)bh * SEQ * DK;
  const u16* Kh = K + (size_t)bh * SEQ * DK;
  const u16* Vh = Vt + (size_t)bh * DK * SEQ;
  __shared__ __align__(16) u16 Plds[4][16][64];  // per-wave P tile, 8 KB

  // A-frag layout: m = lane&15, k = quad*8+j  [m120-verified]
  const int qrow = qb + wave * 16 + l16;
  const bf8v qf0 = *(const bf8v*)&Qh[(size_t)qrow * DK + quad * 8];
  const bf8v qf1 = *(const bf8v*)&Qh[(size_t)qrow * DK + 32 + quad * 8];

  f32x4 o[4];
  float m_r[4], l_r[4];
#pragma unroll
  for (int r = 0; r < 4; r++) { m_r[r] = -1e30f; l_r[r] = 0.f; }
#pragma unroll
  for (int d = 0; d < 4; d++) o[d] = (f32x4){0.f, 0.f, 0.f, 0.f};
  const float scale = 0.125f;  // 1/sqrt(64)

  for (int kt = 0; kt < SEQ; kt += 64) {
    // S tile 16q x 64k per wave: C layout -> lane holds key col l16, rows quad*4+r
    f32x4 s[4];
#pragma unroll
    for (int nb = 0; nb < 4; nb++) {
      const int krow = kt + nb * 16 + l16;
      const bf8v kf0 = *(const bf8v*)&Kh[(size_t)krow * DK + quad * 8];
      const bf8v kf1 = *(const bf8v*)&Kh[(size_t)krow * DK + 32 + quad * 8];
      f32x4 t = (f32x4){0.f, 0.f, 0.f, 0.f};
      t = __builtin_amdgcn_mfma_f32_16x16x32_bf16(qf0, kf0, t, 0, 0, 0);
      t = __builtin_amdgcn_mfma_f32_16x16x32_bf16(qf1, kf1, t, 0, 0, 0);
      s[nb] = t * scale;
    }
    // online softmax: row stats; 16-lane butterfly stays inside each quad group
    float mt[4];
#pragma unroll
    for (int r = 0; r < 4; r++)
      mt[r] = fmaxf(fmaxf(s[0][r], s[1][r]), fmaxf(s[2][r], s[3][r]));
#pragma unroll
    for (int off = 1; off < 16; off <<= 1)
#pragma unroll
      for (int r = 0; r < 4; r++)
        mt[r] = fmaxf(mt[r], __shfl_xor(mt[r], off));
    float al[4], rs[4];
#pragma unroll
    for (int r = 0; r < 4; r++) {
      const float Mn = fmaxf(m_r[r], mt[r]);
      al[r] = __expf(m_r[r] - Mn);
      m_r[r] = Mn;
      rs[r] = 0.f;
    }
#pragma unroll
    for (int nb = 0; nb < 4; nb++)
#pragma unroll
      for (int r = 0; r < 4; r++) {
        const float p = __expf(s[nb][r] - m_r[r]);
        s[nb][r] = p;
        rs[r] += p;
      }
#pragma unroll
    for (int off = 1; off < 16; off <<= 1)
#pragma unroll
      for (int r = 0; r < 4; r++)
        rs[r] += __shfl_xor(rs[r], off);
#pragma unroll
    for (int r = 0; r < 4; r++) l_r[r] = l_r[r] * al[r] + rs[r];
#pragma unroll
    for (int d = 0; d < 4; d++)
#pragma unroll
      for (int r = 0; r < 4; r++) o[d][r] *= al[r];

    // P: C layout -> A layout via LDS round-trip (wave-private region)
#pragma unroll
    for (int nb = 0; nb < 4; nb++)
#pragma unroll
      for (int r = 0; r < 4; r++)
        Plds[wave][quad * 4 + r][nb * 16 + l16] = f2b(s[nb][r]);
    __syncthreads();

    // PV: A = P[q=l16][key=kc*32+quad*8+j], B = V[key][d] from Vt (contiguous)
#pragma unroll
    for (int kc = 0; kc < 2; kc++) {
      const bf8v pf = *(const bf8v*)&Plds[wave][l16][kc * 32 + quad * 8];
#pragma unroll
      for (int d = 0; d < 4; d++) {
        const bf8v vf = *(const bf8v*)&Vh[(size_t)(d * 16 + l16) * SEQ + kt + kc * 32 + quad * 8];
        o[d] = __builtin_amdgcn_mfma_f32_16x16x32_bf16(pf, vf, o[d], 0, 0, 0);
      }
    }
  }

  // epilogue: ctx[b*SEQ+q][h*64 + d*16 + l16], bf16
  float inv[4];
#pragma unroll
  for (int r = 0; r < 4; r++) inv[r] = 1.f / l_r[r];
  const int b = bh >> 4, h = bh & 15;
#pragma unroll
  for (int d = 0; d < 4; d++)
#pragma unroll
    for (int r = 0; r < 4; r++) {
      const int q = qb + wave * 16 + quad * 4 + r;
      const int col = h * 64 + d * 16 + l16;
      ctx[(size_t)(b * SEQ + q) * D_MODEL + col] = f2b(o[d][r] * inv[r]);
    }
}

// -------------------------------- launch ---------------------------------------
extern "C" void kernel_launch(void* const* d_in, const int* in_sizes, int n_in,
                              void* d_out, int out_size, void* d_ws, size_t ws_size,
                              hipStream_t stream) {
  const float* q  = (const float*)d_in[0];
  const float* k  = (const float*)d_in[1];
  const float* v  = (const float*)d_in[2];
  const float* Wq = (const float*)d_in[3];
  const float* bq = (const float*)d_in[4];
  const float* Wk = (const float*)d_in[5];
  const float* bk = (const float*)d_in[6];
  const float* Wv = (const float*)d_in[7];
  const float* bv = (const float*)d_in[8];
  const float* Wo = (const float*)d_in[9];
  const float* bo = (const float*)d_in[10];

  u16* ws  = (u16*)d_ws;
  u16* wt  = ws;                                     // 4 x 1M bf16 (W^T x4) = 8 MB
  u16* act = wt + (size_t)4 * D_MODEL * D_MODEL;     // 8192x1024 bf16 = 16.8 MB (reused)
  u16* Qw  = act + (size_t)ROWS * D_MODEL;
  u16* Kw  = Qw + (size_t)ROWS * D_MODEL;
  u16* Vt  = Kw + (size_t)ROWS * D_MODEL;            // total ~75.6 MB

  const int n4 = ROWS * D_MODEL / 4;                 // 2,097,152 float4 groups
  dim3 gg(ROWS / BM, D_MODEL / BN), gb(256);

  wtrans_cvt_kernel<<<dim3(32, 32, 4), dim3(32, 8), 0, stream>>>(Wq, Wk, Wv, Wo, wt);

  cvt_f2b_kernel<<<n4 / 256, 256, 0, stream>>>(q, act, n4);
  gemm_bt<<<gg, gb, 0, stream>>>(act, wt,                                 bq, Qw, 0);
  cvt_f2b_kernel<<<n4 / 256, 256, 0, stream>>>(k, act, n4);
  gemm_bt<<<gg, gb, 0, stream>>>(act, wt + (size_t)1 * D_MODEL * D_MODEL, bk, Kw, 0);
  cvt_f2b_kernel<<<n4 / 256, 256, 0, stream>>>(v, act, n4);
  gemm_bt<<<gg, gb, 0, stream>>>(act, wt + (size_t)2 * D_MODEL * D_MODEL, bv, Vt, 1);

  attn_kernel<<<dim3(SEQ / 64, BATCH * NHEAD), 256, 0, stream>>>(Qw, Kw, Vt, act);

  gemm_bt<<<gg, gb, 0, stream>>>(act, wt + (size_t)3 * D_MODEL * D_MODEL, bo, d_out, 2);
}

// Round 3
// 518.636 us; speedup vs baseline: 1.5310x; 1.5310x over previous
//
#include <hip/hip_runtime.h>
#include <hip/hip_bf16.h>
#include <cstdint>
#include <cstddef>

// MultiHeadAttention: fp32 in/out. B=4, L=2048, D=1024, H=16, dk=64.
// bf16 MFMA internally, fp32 accumulation.

typedef unsigned short u16;
typedef __bf16 bf8v __attribute__((ext_vector_type(8)));   // MFMA A/B frag (4 VGPRs)
typedef float f32x4 __attribute__((ext_vector_type(4)));   // MFMA C/D frag

#define D_MODEL 1024
#define NHEAD   16
#define DK      64
#define BATCH   4
#define SEQ     2048
#define ROWS    (BATCH * SEQ)   // 8192

__device__ __forceinline__ u16 f2b(float f) {  // RTNE float->bf16
  union { float f; unsigned int i; } x; x.f = f;
  unsigned int r = x.i + 0x7fffu + ((x.i >> 16) & 1u);
  return (u16)(r >> 16);
}
__device__ __forceinline__ void async16(const void* g, void* l) {
  __builtin_amdgcn_global_load_lds((const __attribute__((address_space(1))) void*)g,
                                   (__attribute__((address_space(3))) void*)l, 16, 0, 0);
}
#define MFMA16(a, b, c) __builtin_amdgcn_mfma_f32_16x16x32_bf16(a, b, c, 0, 0, 0)

// -------- weight transpose + downcast: dst[n][k] = bf16(src[k][n]), 4 mats ------
__global__ void wtrans_cvt_kernel(const float* __restrict__ w0, const float* __restrict__ w1,
                                  const float* __restrict__ w2, const float* __restrict__ w3,
                                  u16* __restrict__ dst4) {
  __shared__ float t[32][33];
  const float* src = (blockIdx.z == 0) ? w0 : (blockIdx.z == 1) ? w1
                   : (blockIdx.z == 2) ? w2 : w3;
  u16* dst = dst4 + (size_t)blockIdx.z * D_MODEL * D_MODEL;
  const int c0 = blockIdx.x * 32, r0 = blockIdx.y * 32;
  for (int i = threadIdx.y; i < 32; i += 8)
    t[i][threadIdx.x] = src[(size_t)(r0 + i) * D_MODEL + c0 + threadIdx.x];
  __syncthreads();
  for (int i = threadIdx.y; i < 32; i += 8)
    dst[(size_t)(c0 + i) * D_MODEL + r0 + threadIdx.x] = f2b(t[threadIdx.x][i]);
}

// -------- activation downcast: bf16 dst[i] = src[i], vectorized x4 --------------
__global__ __launch_bounds__(256) void cvt_f2b_kernel(const float* __restrict__ src,
                                                      u16* __restrict__ dst, int n4) {
  const int i = blockIdx.x * 256 + threadIdx.x;
  if (i < n4) {
    const float4 v = ((const float4*)src)[i];
    ushort4 o;
    o.x = f2b(v.x); o.y = f2b(v.y); o.z = f2b(v.z); o.w = f2b(v.w);
    ((ushort4*)dst)[i] = o;
  }
}

// ---------------- GEMM: out = (A[M,1024] @ Bt^T + bias) * oscale ----------------
// mode 0: out bf16 [bh][l][dk]; mode 1: out bf16 [bh][dk][l]; mode 2: out fp32.
#define BM 128
#define BN 128
#define BK 32

__global__ __launch_bounds__(256) void gemm_bt(const u16* __restrict__ A,
                                               const u16* __restrict__ Bt,
                                               const float* __restrict__ bias,
                                               void* __restrict__ out, int mode,
                                               float oscale) {
  __shared__ __align__(16) u16 As[BM * BK];  // 8 KB, [128 m][4 chunks of 8, XOR-swizzled]
  __shared__ __align__(16) u16 Bs[BN * BK];
  const int tid = threadIdx.x;
  const int lane = tid & 63, wave = tid >> 6;
  const int wm = wave >> 1, wn = wave & 1;
  const int quad = lane >> 4, l16 = lane & 15;
  const int m0 = blockIdx.x * BM, n0 = blockIdx.y * BN;
  const int K = 1024;

  f32x4 acc[4][4];
#pragma unroll
  for (int i = 0; i < 4; i++)
#pragma unroll
    for (int j = 0; j < 4; j++) acc[i][j] = (f32x4){0.f, 0.f, 0.f, 0.f};

  const int srow = tid >> 2;
  // source chunk XOR-swizzled by (row>>1)&3 so LDS (linear tid*16B) ends up swizzled
  const int sch = ((tid & 3) ^ ((tid >> 3) & 3)) * 8;
  const int fsw = (quad ^ ((l16 >> 1) & 3)) * 8;   // frag-read swizzled chunk
  const u16* Ag = A + (size_t)(m0 + srow) * K + sch;
  const u16* Bg = Bt + (size_t)(n0 + srow) * K + sch;

  for (int k0 = 0; k0 < K; k0 += BK) {
    async16(Ag + k0, &As[tid * 8]);
    async16(Ag + (size_t)64 * K + k0, &As[2048 + tid * 8]);
    async16(Bg + k0, &Bs[tid * 8]);
    async16(Bg + (size_t)64 * K + k0, &Bs[2048 + tid * 8]);
    __syncthreads();

    bf8v af[4], bfr[4];
#pragma unroll
    for (int i = 0; i < 4; i++)
      af[i] = *(const bf8v*)&As[(wm * 64 + i * 16 + l16) * BK + fsw];
#pragma unroll
    for (int j = 0; j < 4; j++)
      bfr[j] = *(const bf8v*)&Bs[(wn * 64 + j * 16 + l16) * BK + fsw];
#pragma unroll
    for (int i = 0; i < 4; i++)
#pragma unroll
      for (int j = 0; j < 4; j++)
        acc[i][j] = MFMA16(af[i], bfr[j], acc[i][j]);
    __syncthreads();
  }

  // epilogue: C layout col=lane&15, row=quad*4+reg
#pragma unroll
  for (int j = 0; j < 4; j++) {
    const int n = n0 + wn * 64 + j * 16 + l16;
    const float bv = bias[n];
#pragma unroll
    for (int i = 0; i < 4; i++) {
      const int gr0 = m0 + wm * 64 + i * 16 + quad * 4;
#pragma unroll
      for (int r = 0; r < 4; r++) {
        const int row = gr0 + r;
        const float val = (acc[i][j][r] + bv) * oscale;
        if (mode == 2) {
          ((float*)out)[(size_t)row * D_MODEL + n] = val;
        } else {
          const int b = row >> 11, l = row & 2047;
          const int h = n >> 6, d = n & 63;
          if (mode == 0)
            ((u16*)out)[(((size_t)(b * NHEAD + h) * SEQ + l) << 6) + d] = f2b(val);
          else
            ((u16*)out)[(((size_t)(b * NHEAD + h) * DK + d) << 11) + l] = f2b(val);
        }
      }
    }
  }
}

// ---------------- flash attention: block = 128 q rows x one bh ------------------
// Q,K: [bh][SEQ][DK] bf16 (Q pre-scaled by 1/8).  Vt: [bh][DK][SEQ] bf16.
// ctx: [B*SEQ][D_MODEL] bf16.  4 waves, 32 q rows each; K/V tiles (64 keys)
// double-buffered in LDS via async16; all LDS layouts XOR-chunk-swizzled.
__global__ __launch_bounds__(256, 3) void attn_kernel(const u16* __restrict__ Q,
                                                      const u16* __restrict__ K,
                                                      const u16* __restrict__ Vt,
                                                      u16* __restrict__ ctx) {
  const int bh = blockIdx.y;
  const int qb = blockIdx.x * 128;
  const int tid = threadIdx.x;
  const int lane = tid & 63, wave = tid >> 6;
  const int quad = lane >> 4, l16 = lane & 15;
  const u16* Qh = Q + (size_t)bh * SEQ * DK;
  const u16* Kh = K + (size_t)bh * SEQ * DK;
  const u16* Vh = Vt + (size_t)bh * DK * SEQ;

  __shared__ __align__(16) u16 Ks[2][2][64 * 32];  // [buf][d-half][key][32 d swz]  16 KB
  __shared__ __align__(16) u16 Vs[2][2][64 * 32];  // [buf][key-half][d][32 key swz] 16 KB
  __shared__ __align__(16) u16 Ps[4][32 * 64];     // per-wave [32 q][64 key swz]    16 KB

  const int srow = tid >> 2;                         // staging row 0..63
  const int sch  = ((tid & 3) ^ ((tid >> 3) & 3)) * 8;  // swizzled source chunk
  const int ldst = tid * 8;                          // LDS dest (u16), lane*16B
  const int fsw  = (quad ^ ((l16 >> 1) & 3)) * 8;    // K/V frag swizzled chunk

  // Q frags, A layout: A[m=lane&15][k=quad*8+j]
  bf8v qf[2][2];
#pragma unroll
  for (int qg = 0; qg < 2; qg++)
#pragma unroll
    for (int h = 0; h < 2; h++)
      qf[qg][h] = *(const bf8v*)&Qh[(size_t)(qb + wave * 32 + qg * 16 + l16) * DK + h * 32 + quad * 8];

  f32x4 o[2][4];
  float m_r[2][4], l_r[2][4];
#pragma unroll
  for (int qg = 0; qg < 2; qg++)
#pragma unroll
    for (int r = 0; r < 4; r++) { m_r[qg][r] = -1e30f; l_r[qg][r] = 0.f; }
#pragma unroll
  for (int qg = 0; qg < 2; qg++)
#pragma unroll
    for (int d = 0; d < 4; d++) o[qg][d] = (f32x4){0.f, 0.f, 0.f, 0.f};

  // prologue: stage tile 0 into buf 0
  async16(Kh + (size_t)srow * DK + sch,            &Ks[0][0][ldst]);
  async16(Kh + (size_t)srow * DK + 32 + sch,       &Ks[0][1][ldst]);
  async16(Vh + (size_t)srow * SEQ + sch,           &Vs[0][0][ldst]);
  async16(Vh + (size_t)srow * SEQ + 32 + sch,      &Vs[0][1][ldst]);
  __syncthreads();

  int p = 0;
  for (int kt = 0; kt < SEQ; kt += 64) {
    const int nt = kt + 64;
    if (nt < SEQ) {  // prefetch next tile into buf p^1 (drained by end barrier)
      async16(Kh + (size_t)(nt + srow) * DK + sch,      &Ks[p ^ 1][0][ldst]);
      async16(Kh + (size_t)(nt + srow) * DK + 32 + sch, &Ks[p ^ 1][1][ldst]);
      async16(Vh + (size_t)srow * SEQ + nt + sch,       &Vs[p ^ 1][0][ldst]);
      async16(Vh + (size_t)srow * SEQ + nt + 32 + sch,  &Vs[p ^ 1][1][ldst]);
    }

    // ---- QK^T: S[32 q][64 keys] per wave (Q pre-scaled) ----
    bf8v kf[4][2];
#pragma unroll
    for (int nb = 0; nb < 4; nb++)
#pragma unroll
      for (int h = 0; h < 2; h++)
        kf[nb][h] = *(const bf8v*)&Ks[p][h][(nb * 16 + l16) * 32 + fsw];
    f32x4 s[2][4];
#pragma unroll
    for (int qg = 0; qg < 2; qg++)
#pragma unroll
      for (int nb = 0; nb < 4; nb++) {
        f32x4 t = (f32x4){0.f, 0.f, 0.f, 0.f};
        t = MFMA16(qf[qg][0], kf[nb][0], t);
        t = MFMA16(qf[qg][1], kf[nb][1], t);
        s[qg][nb] = t;
      }

    // ---- online softmax per 16-row group (rows quad*4+r, 16 key-lanes) ----
#pragma unroll
    for (int qg = 0; qg < 2; qg++) {
      float mt[4], al[4], rs[4];
#pragma unroll
      for (int r = 0; r < 4; r++)
        mt[r] = fmaxf(fmaxf(s[qg][0][r], s[qg][1][r]), fmaxf(s[qg][2][r], s[qg][3][r]));
#pragma unroll
      for (int off = 1; off < 16; off <<= 1)
#pragma unroll
        for (int r = 0; r < 4; r++)
          mt[r] = fmaxf(mt[r], __shfl_xor(mt[r], off));
#pragma unroll
      for (int r = 0; r < 4; r++) {
        const float Mn = fmaxf(m_r[qg][r], mt[r]);
        al[r] = __expf(m_r[qg][r] - Mn);
        m_r[qg][r] = Mn;
        rs[r] = 0.f;
      }
#pragma unroll
      for (int nb = 0; nb < 4; nb++)
#pragma unroll
        for (int r = 0; r < 4; r++) {
          const float pv = __expf(s[qg][nb][r] - m_r[qg][r]);
          s[qg][nb][r] = pv;
          rs[r] += pv;
        }
#pragma unroll
      for (int off = 1; off < 16; off <<= 1)
#pragma unroll
        for (int r = 0; r < 4; r++)
          rs[r] += __shfl_xor(rs[r], off);
#pragma unroll
      for (int r = 0; r < 4; r++) l_r[qg][r] = l_r[qg][r] * al[r] + rs[r];
#pragma unroll
      for (int d = 0; d < 4; d++)
#pragma unroll
        for (int r = 0; r < 4; r++) o[qg][d][r] *= al[r];

      // P: C layout -> A layout, wave-private LDS, chunk ^= (row&7)
#pragma unroll
      for (int nb = 0; nb < 4; nb++)
#pragma unroll
        for (int r = 0; r < 4; r++) {
          const int row = qg * 16 + quad * 4 + r;
          Ps[wave][row * 64 + (((nb * 2 + (l16 >> 3)) ^ (row & 7)) * 8) + (l16 & 7)] =
              f2b(s[qg][nb][r]);
        }
    }

    // ---- PV: O += P @ V ----
    bf8v vf[4][2], pf[2][2];
#pragma unroll
    for (int dc = 0; dc < 4; dc++)
#pragma unroll
      for (int kc = 0; kc < 2; kc++)
        vf[dc][kc] = *(const bf8v*)&Vs[p][kc][(dc * 16 + l16) * 32 + fsw];
#pragma unroll
    for (int qg = 0; qg < 2; qg++)
#pragma unroll
      for (int kc = 0; kc < 2; kc++)
        pf[qg][kc] = *(const bf8v*)&Ps[wave][(qg * 16 + l16) * 64 + (((kc * 4 + quad) ^ (l16 & 7)) * 8)];
#pragma unroll
    for (int qg = 0; qg < 2; qg++)
#pragma unroll
      for (int dc = 0; dc < 4; dc++) {
        o[qg][dc] = MFMA16(pf[qg][0], vf[dc][0], o[qg][dc]);
        o[qg][dc] = MFMA16(pf[qg][1], vf[dc][1], o[qg][dc]);
      }

    __syncthreads();  // buf p reads done; prefetch into p^1 drained
    p ^= 1;
  }

  // epilogue: ctx[b*SEQ+q][h*64 + dc*16 + l16]
  const int b = bh >> 4, hh = bh & 15;
#pragma unroll
  for (int qg = 0; qg < 2; qg++) {
    float inv[4];
#pragma unroll
    for (int r = 0; r < 4; r++) inv[r] = 1.f / l_r[qg][r];
#pragma unroll
    for (int dc = 0; dc < 4; dc++)
#pragma unroll
      for (int r = 0; r < 4; r++) {
        const int q = qb + wave * 32 + qg * 16 + quad * 4 + r;
        const int col = hh * 64 + dc * 16 + l16;
        ctx[(size_t)(b * SEQ + q) * D_MODEL + col] = f2b(o[qg][dc][r] * inv[r]);
      }
  }
}

// -------------------------------- launch ---------------------------------------
extern "C" void kernel_launch(void* const* d_in, const int* in_sizes, int n_in,
                              void* d_out, int out_size, void* d_ws, size_t ws_size,
                              hipStream_t stream) {
  const float* q  = (const float*)d_in[0];
  const float* k  = (const float*)d_in[1];
  const float* v  = (const float*)d_in[2];
  const float* Wq = (const float*)d_in[3];
  const float* bq = (const float*)d_in[4];
  const float* Wk = (const float*)d_in[5];
  const float* bk = (const float*)d_in[6];
  const float* Wv = (const float*)d_in[7];
  const float* bv = (const float*)d_in[8];
  const float* Wo = (const float*)d_in[9];
  const float* bo = (const float*)d_in[10];

  u16* ws  = (u16*)d_ws;
  u16* wt  = ws;                                     // 4 x 1M bf16 (W^T x4) = 8 MB
  u16* act = wt + (size_t)4 * D_MODEL * D_MODEL;     // 16.8 MB staging (reused)
  u16* Qw  = act + (size_t)ROWS * D_MODEL;
  u16* Kw  = Qw + (size_t)ROWS * D_MODEL;
  u16* Vt  = Kw + (size_t)ROWS * D_MODEL;            // total ~75.6 MB

  const int n4 = ROWS * D_MODEL / 4;
  dim3 gg(ROWS / BM, D_MODEL / BN), gb(256);

  wtrans_cvt_kernel<<<dim3(32, 32, 4), dim3(32, 8), 0, stream>>>(Wq, Wk, Wv, Wo, wt);

  cvt_f2b_kernel<<<n4 / 256, 256, 0, stream>>>(q, act, n4);
  gemm_bt<<<gg, gb, 0, stream>>>(act, wt,                                 bq, Qw, 0, 0.125f);
  cvt_f2b_kernel<<<n4 / 256, 256, 0, stream>>>(k, act, n4);
  gemm_bt<<<gg, gb, 0, stream>>>(act, wt + (size_t)1 * D_MODEL * D_MODEL, bk, Kw, 0, 1.0f);
  cvt_f2b_kernel<<<n4 / 256, 256, 0, stream>>>(v, act, n4);
  gemm_bt<<<gg, gb, 0, stream>>>(act, wt + (size_t)2 * D_MODEL * D_MODEL, bv, Vt, 1, 1.0f);

  attn_kernel<<<dim3(SEQ / 128, BATCH * NHEAD), 256, 0, stream>>>(Qw, Kw, Vt, act);

  gemm_bt<<<gg, gb, 0, stream>>>(act, wt + (size_t)3 * D_MODEL * D_MODEL, bo, d_out, 2, 1.0f);
}

// Round 4
// 401.741 us; speedup vs baseline: 1.9765x; 1.2910x over previous
//
#include <hip/hip_runtime.h>
#include <hip/hip_bf16.h>
#include <cstdint>
#include <cstddef>

// MultiHeadAttention: fp32 in/out. B=4, L=2048, D=1024, H=16, dk=64.
// bf16 MFMA internally, fp32 accumulation.

typedef unsigned short u16;
typedef __bf16 bf8v __attribute__((ext_vector_type(8)));   // MFMA A/B frag (4 VGPRs)
typedef __bf16 bf4v __attribute__((ext_vector_type(4)));
typedef float f32x4 __attribute__((ext_vector_type(4)));   // MFMA C/D frag

#define D_MODEL 1024
#define NHEAD   16
#define DK      64
#define BATCH   4
#define SEQ     2048
#define ROWS    (BATCH * SEQ)   // 8192

__device__ __forceinline__ u16 f2b(float f) {  // RTNE float->bf16
  union { float f; unsigned int i; } x; x.f = f;
  unsigned int r = x.i + 0x7fffu + ((x.i >> 16) & 1u);
  return (u16)(r >> 16);
}
__device__ __forceinline__ ushort4 pack4(float a, float b, float c, float d) {
  union { bf4v v; ushort4 u; } x;
  x.v[0] = (__bf16)a; x.v[1] = (__bf16)b; x.v[2] = (__bf16)c; x.v[3] = (__bf16)d;
  return x.u;
}
__device__ __forceinline__ void async16(const void* g, void* l) {
  __builtin_amdgcn_global_load_lds((const __attribute__((address_space(1))) void*)g,
                                   (__attribute__((address_space(3))) void*)l, 16, 0, 0);
}
#define MFMA16(a, b, c) __builtin_amdgcn_mfma_f32_16x16x32_bf16(a, b, c, 0, 0, 0)

// -------- weight transpose + downcast: dst[n][k] = bf16(src[k][n]), 4 mats ------
__global__ void wtrans_cvt_kernel(const float* __restrict__ w0, const float* __restrict__ w1,
                                  const float* __restrict__ w2, const float* __restrict__ w3,
                                  u16* __restrict__ dst4) {
  __shared__ float t[32][33];
  const float* src = (blockIdx.z == 0) ? w0 : (blockIdx.z == 1) ? w1
                   : (blockIdx.z == 2) ? w2 : w3;
  u16* dst = dst4 + (size_t)blockIdx.z * D_MODEL * D_MODEL;
  const int c0 = blockIdx.x * 32, r0 = blockIdx.y * 32;
  for (int i = threadIdx.y; i < 32; i += 8)
    t[i][threadIdx.x] = src[(size_t)(r0 + i) * D_MODEL + c0 + threadIdx.x];
  __syncthreads();
  for (int i = threadIdx.y; i < 32; i += 8)
    dst[(size_t)(c0 + i) * D_MODEL + r0 + threadIdx.x] = f2b(t[threadIdx.x][i]);
}

// -------- activation downcast: bf16 dst[i] = src[i], vectorized x4 --------------
__global__ __launch_bounds__(256) void cvt_f2b_kernel(const float* __restrict__ src,
                                                      u16* __restrict__ dst, int n4) {
  const int i = blockIdx.x * 256 + threadIdx.x;
  if (i < n4) {
    const float4 v = ((const float4*)src)[i];
    ushort4 o;
    o.x = f2b(v.x); o.y = f2b(v.y); o.z = f2b(v.z); o.w = f2b(v.w);
    ((ushort4*)dst)[i] = o;
  }
}

// ---------------- GEMM: out = (A[M,1024] @ Bt^T + bias) * oscale ----------------
// mode 0: out bf16 [bh][l][dk]; mode 1: out bf16 [bh][dk][l]; mode 2: out fp32.
#define BM 128
#define BN 128
#define BK 32

__global__ __launch_bounds__(256) void gemm_bt(const u16* __restrict__ A,
                                               const u16* __restrict__ Bt,
                                               const float* __restrict__ bias,
                                               void* __restrict__ out, int mode,
                                               float oscale) {
  __shared__ __align__(16) u16 As[BM * BK];  // 8 KB, XOR-chunk-swizzled rows
  __shared__ __align__(16) u16 Bs[BN * BK];
  const int tid = threadIdx.x;
  const int lane = tid & 63, wave = tid >> 6;
  const int wm = wave >> 1, wn = wave & 1;
  const int quad = lane >> 4, l16 = lane & 15;
  const int m0 = blockIdx.x * BM, n0 = blockIdx.y * BN;
  const int K = 1024;

  f32x4 acc[4][4];
#pragma unroll
  for (int i = 0; i < 4; i++)
#pragma unroll
    for (int j = 0; j < 4; j++) acc[i][j] = (f32x4){0.f, 0.f, 0.f, 0.f};

  const int srow = tid >> 2;
  const int sch = ((tid & 3) ^ ((tid >> 3) & 3)) * 8;
  const int fsw = (quad ^ ((l16 >> 1) & 3)) * 8;
  const u16* Ag = A + (size_t)(m0 + srow) * K + sch;
  const u16* Bg = Bt + (size_t)(n0 + srow) * K + sch;

  for (int k0 = 0; k0 < K; k0 += BK) {
    async16(Ag + k0, &As[tid * 8]);
    async16(Ag + (size_t)64 * K + k0, &As[2048 + tid * 8]);
    async16(Bg + k0, &Bs[tid * 8]);
    async16(Bg + (size_t)64 * K + k0, &Bs[2048 + tid * 8]);
    __syncthreads();

    bf8v af[4], bfr[4];
#pragma unroll
    for (int i = 0; i < 4; i++)
      af[i] = *(const bf8v*)&As[(wm * 64 + i * 16 + l16) * BK + fsw];
#pragma unroll
    for (int j = 0; j < 4; j++)
      bfr[j] = *(const bf8v*)&Bs[(wn * 64 + j * 16 + l16) * BK + fsw];
#pragma unroll
    for (int i = 0; i < 4; i++)
#pragma unroll
      for (int j = 0; j < 4; j++)
        acc[i][j] = MFMA16(af[i], bfr[j], acc[i][j]);
    __syncthreads();
  }

  // epilogue: C layout col=lane&15, row=quad*4+reg
#pragma unroll
  for (int j = 0; j < 4; j++) {
    const int n = n0 + wn * 64 + j * 16 + l16;
    const float bv = bias[n];
#pragma unroll
    for (int i = 0; i < 4; i++) {
      const int gr0 = m0 + wm * 64 + i * 16 + quad * 4;
#pragma unroll
      for (int r = 0; r < 4; r++) {
        const int row = gr0 + r;
        const float val = (acc[i][j][r] + bv) * oscale;
        if (mode == 2) {
          ((float*)out)[(size_t)row * D_MODEL + n] = val;
        } else {
          const int b = row >> 11, l = row & 2047;
          const int h = n >> 6, d = n & 63;
          if (mode == 0)
            ((u16*)out)[(((size_t)(b * NHEAD + h) * SEQ + l) << 6) + d] = f2b(val);
          else
            ((u16*)out)[(((size_t)(b * NHEAD + h) * DK + d) << 11) + l] = f2b(val);
        }
      }
    }
  }
}

// ---------------- flash attention (S^T form): block = 128 q rows x one bh -------
// Q,K: [bh][SEQ][DK] bf16, Q pre-scaled by 0.125*log2e (exp2-domain softmax).
// Vt: [bh][DK][SEQ] bf16.  ctx: [B*SEQ][D_MODEL] bf16.
// S^T = K·Q^T via MFMA operand swap: C layout puts q in lane&15, keys in
// quad*4+reg -> softmax reduces in-register + 2 shfl rounds (xor 16,32);
// P^T written as b64, read back as PV B-operand b128; O^T = V^T·P^T.
__global__ __launch_bounds__(256, 3) void attn_kernel(const u16* __restrict__ Q,
                                                      const u16* __restrict__ K,
                                                      const u16* __restrict__ Vt,
                                                      u16* __restrict__ ctx) {
  const int bh = blockIdx.y;
  const int qb = blockIdx.x * 128;
  const int tid = threadIdx.x;
  const int lane = tid & 63, wave = tid >> 6;
  const int quad = lane >> 4, l16 = lane & 15;
  const u16* Qh = Q + (size_t)bh * SEQ * DK;
  const u16* Kh = K + (size_t)bh * SEQ * DK;
  const u16* Vh = Vt + (size_t)bh * DK * SEQ;

  __shared__ __align__(16) u16 Ks[2][2][64 * 32];  // [buf][d-half][key][32 d swz]   16 KB
  __shared__ __align__(16) u16 Vs[2][2][64 * 32];  // [buf][key-half][d][32 key swz] 16 KB
  __shared__ __align__(16) u16 Ps[4][32 * 64];     // per-wave P^T region            16 KB

  const int srow = tid >> 2;
  const int sch  = ((tid & 3) ^ ((tid >> 3) & 3)) * 8;
  const int ldst = tid * 8;
  const int fsw  = (quad ^ ((l16 >> 1) & 3)) * 8;

  // Q frags (dual-use A/B layout: lane&15 = q, quad*8+j = d)
  bf8v qf[2][2];
#pragma unroll
  for (int qg = 0; qg < 2; qg++)
#pragma unroll
    for (int h = 0; h < 2; h++)
      qf[qg][h] = *(const bf8v*)&Qh[(size_t)(qb + wave * 32 + qg * 16 + l16) * DK + h * 32 + quad * 8];

  f32x4 o[2][4];      // O^T acc: lane&15 = q, quad*4+r = d (within dc block)
  float m_q[2], l_q[2];  // per-lane softmax state for q = qg*16 + l16
#pragma unroll
  for (int qg = 0; qg < 2; qg++) {
    m_q[qg] = -1e30f; l_q[qg] = 0.f;
#pragma unroll
    for (int d = 0; d < 4; d++) o[qg][d] = (f32x4){0.f, 0.f, 0.f, 0.f};
  }

  // prologue: stage tile 0 into buf 0
  async16(Kh + (size_t)srow * DK + sch,       &Ks[0][0][ldst]);
  async16(Kh + (size_t)srow * DK + 32 + sch,  &Ks[0][1][ldst]);
  async16(Vh + (size_t)srow * SEQ + sch,      &Vs[0][0][ldst]);
  async16(Vh + (size_t)srow * SEQ + 32 + sch, &Vs[0][1][ldst]);
  __syncthreads();

  int p = 0;
  for (int kt = 0; kt < SEQ; kt += 64) {
    const int nt = kt + 64;
    if (nt < SEQ) {  // prefetch next tile (drained by end-of-loop barrier)
      async16(Kh + (size_t)(nt + srow) * DK + sch,      &Ks[p ^ 1][0][ldst]);
      async16(Kh + (size_t)(nt + srow) * DK + 32 + sch, &Ks[p ^ 1][1][ldst]);
      async16(Vh + (size_t)srow * SEQ + nt + sch,       &Vs[p ^ 1][0][ldst]);
      async16(Vh + (size_t)srow * SEQ + nt + 32 + sch,  &Vs[p ^ 1][1][ldst]);
    }

    bf8v kf[4][2];
#pragma unroll
    for (int nb = 0; nb < 4; nb++)
#pragma unroll
      for (int h = 0; h < 2; h++)
        kf[nb][h] = *(const bf8v*)&Ks[p][h][(nb * 16 + l16) * 32 + fsw];

#pragma unroll
    for (int qg = 0; qg < 2; qg++) {
      // S^T tile: lane holds S[key = nb*16+quad*4+r][q = qg*16+l16]
      f32x4 s[4];
#pragma unroll
      for (int nb = 0; nb < 4; nb++) {
        f32x4 t = (f32x4){0.f, 0.f, 0.f, 0.f};
        t = MFMA16(kf[nb][0], qf[qg][0], t);
        t = MFMA16(kf[nb][1], qf[qg][1], t);
        s[nb] = t;
      }
      // online softmax (exp2 domain): in-lane over 16, cross-quad via 2 shfl
      float mx = s[0][0];
#pragma unroll
      for (int nb = 0; nb < 4; nb++)
#pragma unroll
        for (int r = 0; r < 4; r++) mx = fmaxf(mx, s[nb][r]);
      mx = fmaxf(mx, __shfl_xor(mx, 16));
      mx = fmaxf(mx, __shfl_xor(mx, 32));
      const float Mn = fmaxf(m_q[qg], mx);
      const float al = __builtin_amdgcn_exp2f(m_q[qg] - Mn);
      m_q[qg] = Mn;
      float rs = 0.f;
#pragma unroll
      for (int nb = 0; nb < 4; nb++)
#pragma unroll
        for (int r = 0; r < 4; r++) {
          const float pv = __builtin_amdgcn_exp2f(s[nb][r] - Mn);
          s[nb][r] = pv;
          rs += pv;
        }
      rs += __shfl_xor(rs, 16);
      rs += __shfl_xor(rs, 32);
      l_q[qg] = l_q[qg] * al + rs;
#pragma unroll
      for (int d = 0; d < 4; d++) o[qg][d] *= al;

      // P^T -> LDS: row q, chunk (key>>3) ^ (q&7); lane writes 4 consecutive keys
      const int prow = (wave * 32 + qg * 16 + l16) * 64;
#pragma unroll
      for (int nb = 0; nb < 4; nb++) {
        const int cp = (nb * 2 + (quad >> 1)) ^ (l16 & 7);
        *(ushort4*)&Ps[0][prow + cp * 8 + (quad & 1) * 4] =
            pack4(s[nb][0], s[nb][1], s[nb][2], s[nb][3]);
      }
    }

    // PV: O^T += V^T @ P^T.  A = Vt frag, B = P^T frag (b128, swizzled chunk)
    bf8v vf[4][2], pf[2][2];
#pragma unroll
    for (int dc = 0; dc < 4; dc++)
#pragma unroll
      for (int kc = 0; kc < 2; kc++)
        vf[dc][kc] = *(const bf8v*)&Vs[p][kc][(dc * 16 + l16) * 32 + fsw];
#pragma unroll
    for (int qg = 0; qg < 2; qg++)
#pragma unroll
      for (int kc = 0; kc < 2; kc++)
        pf[qg][kc] = *(const bf8v*)&Ps[0][(wave * 32 + qg * 16 + l16) * 64 +
                                         (((kc * 4 + quad) ^ (l16 & 7)) * 8)];
#pragma unroll
    for (int qg = 0; qg < 2; qg++)
#pragma unroll
      for (int dc = 0; dc < 4; dc++) {
        o[qg][dc] = MFMA16(vf[dc][0], pf[qg][0], o[qg][dc]);
        o[qg][dc] = MFMA16(vf[dc][1], pf[qg][1], o[qg][dc]);
      }

    __syncthreads();  // buf p reads done; prefetch into p^1 drained
    p ^= 1;
  }

  // epilogue: O^T lane holds q = l16 col block; write 4 consecutive d as b64
  const int b = bh >> 4, hh = bh & 15;
#pragma unroll
  for (int qg = 0; qg < 2; qg++) {
    const float inv = __builtin_amdgcn_rcpf(l_q[qg]);
    const int q = qb + wave * 32 + qg * 16 + l16;
#pragma unroll
    for (int dc = 0; dc < 4; dc++) {
      const int col = hh * 64 + dc * 16 + quad * 4;
      *(ushort4*)&ctx[(size_t)(b * SEQ + q) * D_MODEL + col] =
          pack4(o[qg][dc][0] * inv, o[qg][dc][1] * inv,
                o[qg][dc][2] * inv, o[qg][dc][3] * inv);
    }
  }
}

// -------------------------------- launch ---------------------------------------
extern "C" void kernel_launch(void* const* d_in, const int* in_sizes, int n_in,
                              void* d_out, int out_size, void* d_ws, size_t ws_size,
                              hipStream_t stream) {
  const float* q  = (const float*)d_in[0];
  const float* k  = (const float*)d_in[1];
  const float* v  = (const float*)d_in[2];
  const float* Wq = (const float*)d_in[3];
  const float* bq = (const float*)d_in[4];
  const float* Wk = (const float*)d_in[5];
  const float* bk = (const float*)d_in[6];
  const float* Wv = (const float*)d_in[7];
  const float* bv = (const float*)d_in[8];
  const float* Wo = (const float*)d_in[9];
  const float* bo = (const float*)d_in[10];

  u16* ws  = (u16*)d_ws;
  u16* wt  = ws;                                     // 4 x 1M bf16 (W^T x4) = 8 MB
  u16* act = wt + (size_t)4 * D_MODEL * D_MODEL;     // 16.8 MB staging (reused)
  u16* Qw  = act + (size_t)ROWS * D_MODEL;
  u16* Kw  = Qw + (size_t)ROWS * D_MODEL;
  u16* Vt  = Kw + (size_t)ROWS * D_MODEL;            // total ~75.6 MB

  const int n4 = ROWS * D_MODEL / 4;
  dim3 gg(ROWS / BM, D_MODEL / BN), gb(256);
  const float QSCALE = 0.18033688011112042f;  // 0.125 * log2(e) -> exp2-domain softmax

  wtrans_cvt_kernel<<<dim3(32, 32, 4), dim3(32, 8), 0, stream>>>(Wq, Wk, Wv, Wo, wt);

  cvt_f2b_kernel<<<n4 / 256, 256, 0, stream>>>(q, act, n4);
  gemm_bt<<<gg, gb, 0, stream>>>(act, wt,                                 bq, Qw, 0, QSCALE);
  cvt_f2b_kernel<<<n4 / 256, 256, 0, stream>>>(k, act, n4);
  gemm_bt<<<gg, gb, 0, stream>>>(act, wt + (size_t)1 * D_MODEL * D_MODEL, bk, Kw, 0, 1.0f);
  cvt_f2b_kernel<<<n4 / 256, 256, 0, stream>>>(v, act, n4);
  gemm_bt<<<gg, gb, 0, stream>>>(act, wt + (size_t)2 * D_MODEL * D_MODEL, bv, Vt, 1, 1.0f);

  attn_kernel<<<dim3(SEQ / 128, BATCH * NHEAD), 256, 0, stream>>>(Qw, Kw, Vt, act);

  gemm_bt<<<gg, gb, 0, stream>>>(act, wt + (size_t)3 * D_MODEL * D_MODEL, bo, d_out, 2, 1.0f);
}